// Round 2
// 3887.720 us; speedup vs baseline: 1.0936x; 1.0936x over previous
//
#include <hip/hip_runtime.h>
#include <math.h>

#define TT 128
#define NF 512
#define HH 1024
#define WROWS (NF + HH)       // 1536
#define NB 256                // one block per 4-output-column group
#define COLS 4
#define SPIN_LIMIT (1 << 22)  // bounded spin: hang -> wrong answer, not dead container

// Poll a ready flag: RELAXED in the loop (agent-scope atomics read the
// coherence point, so values are fresh), periodic ACQUIRE as liveness
// insurance, one-shot ACQUIRE on exit to order subsequent data loads.
__device__ __forceinline__ void spin_flag(const int* __restrict__ f) {
  int guard = 0;
  while (__hip_atomic_load(f, __ATOMIC_RELAXED, __HIP_MEMORY_SCOPE_AGENT) ==
         0) {
    if (++guard >= SPIN_LIMIT) break;
    if ((guard & 127) == 0)
      (void)__hip_atomic_load(f, __ATOMIC_ACQUIRE, __HIP_MEMORY_SCOPE_AGENT);
    __builtin_amdgcn_s_sleep(1);
  }
  (void)__hip_atomic_load(f, __ATOMIC_ACQUIRE, __HIP_MEMORY_SCOPE_AGENT);
}

// One recurrence step for block g (cols gcol0..gcol0+3).
// Thread covers rows tid+256*i of z=[x_t; h_{t-1}]: i=0,1 are x-rows,
// i=2..5 are h-rows. CUR holds W[t] slice; NXT gets W[t+1] prefetched
// BEFORE the poll so HBM streaming overlaps the serial sync chain.
__device__ __forceinline__ void rnn_step(
    const int t, float4 (&CUR)[6], float4 (&NXT)[6], const float xc0,
    const float xc1, const float bc, float& xn0, float& xn1, float& bn,
    const float* __restrict__ Wb, const float* __restrict__ x,
    const float* __restrict__ h_in, const float* __restrict__ bs,
    float* __restrict__ h_buf, int* __restrict__ ready,
    float* __restrict__ out, float (*pacc)[COLS], const int tid, const int g,
    const int gcol0, const int w) {
  const size_t WSTEP = (size_t)WROWS * HH;

  // ---- prefetch step t+1 inputs (independent of the recurrence) ----
  if (t + 1 < TT) {
    const float* p = Wb + (size_t)(t + 1) * WSTEP;
#pragma unroll
    for (int i = 0; i < 6; ++i)
      NXT[i] = *(const float4*)(p + (size_t)(i * 256) * HH);
    xn0 = x[(t + 1) * NF + tid];
    xn1 = x[(t + 1) * NF + 256 + tid];
    bn = bs[(t + 1) * HH + gcol0 + (tid & 3)];
  }

  // ---- obtain h_{t-1} ----
  float h0, h1, h2, h3;
  if (t == 0) {
    h0 = h_in[tid];
    h1 = h_in[256 + tid];
    h2 = h_in[512 + tid];
    h3 = h_in[768 + tid];
  } else {
    spin_flag(&ready[(t - 1) * NB + tid]);  // thread tid polls producer tid
    __syncthreads();  // A: all 256 flags observed -> all h published
    const float* hb = h_buf + (size_t)(t - 1) * HH;
    h0 = __hip_atomic_load(hb + tid, __ATOMIC_RELAXED,
                           __HIP_MEMORY_SCOPE_AGENT);
    h1 = __hip_atomic_load(hb + 256 + tid, __ATOMIC_RELAXED,
                           __HIP_MEMORY_SCOPE_AGENT);
    h2 = __hip_atomic_load(hb + 512 + tid, __ATOMIC_RELAXED,
                           __HIP_MEMORY_SCOPE_AGENT);
    h3 = __hip_atomic_load(hb + 768 + tid, __ATOMIC_RELAXED,
                           __HIP_MEMORY_SCOPE_AGENT);
  }

  // ---- partial dot over this thread's 6 rows ----
  float4 s;
  s.x = xc0 * CUR[0].x + xc1 * CUR[1].x + h0 * CUR[2].x + h1 * CUR[3].x +
        h2 * CUR[4].x + h3 * CUR[5].x;
  s.y = xc0 * CUR[0].y + xc1 * CUR[1].y + h0 * CUR[2].y + h1 * CUR[3].y +
        h2 * CUR[4].y + h3 * CUR[5].y;
  s.z = xc0 * CUR[0].z + xc1 * CUR[1].z + h0 * CUR[2].z + h1 * CUR[3].z +
        h2 * CUR[4].z + h3 * CUR[5].z;
  s.w = xc0 * CUR[0].w + xc1 * CUR[1].w + h0 * CUR[2].w + h1 * CUR[3].w +
        h2 * CUR[4].w + h3 * CUR[5].w;

  // ---- full-wave reduce (all 64 lanes hold the same 4 cols) ----
#pragma unroll
  for (int m = 1; m <= 32; m <<= 1) {
    s.x += __shfl_xor(s.x, m);
    s.y += __shfl_xor(s.y, m);
    s.z += __shfl_xor(s.z, m);
    s.w += __shfl_xor(s.w, m);
  }
  if ((tid & 63) == 0) {
    pacc[w][0] = s.x;
    pacc[w][1] = s.y;
    pacc[w][2] = s.z;
    pacc[w][3] = s.w;
  }
  __syncthreads();  // C: per-wave partials in LDS

  // ---- combine 4 waves, tanh, publish ----
  if (tid < COLS) {
    const float v =
        pacc[0][tid] + pacc[1][tid] + pacc[2][tid] + pacc[3][tid] + bc;
    const float hv = tanhf(v);
    __hip_atomic_store(&h_buf[(size_t)t * HH + gcol0 + tid], hv,
                       __ATOMIC_RELAXED, __HIP_MEMORY_SCOPE_AGENT);
    if (t == TT - 1) out[2 + gcol0 + tid] = hv;
  }
  // tid 0 is in the same wave as the 4 h-stores: release orders them
  if (tid == 0)
    __hip_atomic_store(&ready[t * NB + g], 1, __ATOMIC_RELEASE,
                       __HIP_MEMORY_SCOPE_AGENT);
}

__global__ __launch_bounds__(256, 1) void pg_rnn(
    const float* __restrict__ x, const float* __restrict__ h_in,
    const float* __restrict__ Ws, const float* __restrict__ bs,
    const float* __restrict__ Wout, const float* __restrict__ bout,
    float* __restrict__ h_buf, int* __restrict__ ready,
    float* __restrict__ out) {
  const int tid = threadIdx.x;
  const int g = blockIdx.x;  // column group 0..255
  const int w = tid >> 6;    // wave 0..3
  const int gcol0 = g * COLS;

  __shared__ float pacc[4][COLS];
  __shared__ float red[512];

  // per-thread W base: row tid, this block's 4 cols
  const float* Wb = Ws + (size_t)tid * HH + gcol0;

  float4 A[6], B[6];
  float xa0, xa1, xb0, xb1, ba, bb;
#pragma unroll
  for (int i = 0; i < 6; ++i)
    A[i] = *(const float4*)(Wb + (size_t)(i * 256) * HH);
  xa0 = x[tid];
  xa1 = x[256 + tid];
  ba = bs[gcol0 + (tid & 3)];

  for (int t = 0; t < TT; t += 2) {
    rnn_step(t, A, B, xa0, xa1, ba, xb0, xb1, bb, Wb, x, h_in, bs, h_buf,
             ready, out, pacc, tid, g, gcol0, w);
    rnn_step(t + 1, B, A, xb0, xb1, bb, xa0, xa1, ba, Wb, x, h_in, bs, h_buf,
             ready, out, pacc, tid, g, gcol0, w);
  }

  // ---- epilogue: block 0 computes the 2 actor outputs ----
  if (g == 0) {
    spin_flag(&ready[(TT - 1) * NB + tid]);
    __syncthreads();
    float a0 = 0.f, a1 = 0.f;
#pragma unroll
    for (int i = 0; i < 4; ++i) {
      const int k = tid + 256 * i;
      const float v =
          __hip_atomic_load(&h_buf[(size_t)(TT - 1) * HH + k],
                            __ATOMIC_RELAXED, __HIP_MEMORY_SCOPE_AGENT);
      a0 += v * Wout[k * 2 + 0];
      a1 += v * Wout[k * 2 + 1];
    }
    red[tid] = a0;
    red[256 + tid] = a1;
    __syncthreads();
    for (int s = 128; s > 0; s >>= 1) {
      if (tid < s) {
        red[tid] += red[tid + s];
        red[256 + tid] += red[256 + tid + s];
      }
      __syncthreads();
    }
    if (tid == 0) {
      out[0] = red[0] + bout[0];
      out[1] = red[256] + bout[1];
    }
  }
}

extern "C" void kernel_launch(void* const* d_in, const int* in_sizes, int n_in,
                              void* d_out, int out_size, void* d_ws,
                              size_t ws_size, hipStream_t stream) {
  const float* x = (const float*)d_in[0];
  const float* h = (const float*)d_in[1];
  const float* Ws = (const float*)d_in[2];
  const float* bs = (const float*)d_in[3];
  const float* Wout = (const float*)d_in[4];
  const float* bout = (const float*)d_in[5];
  float* out = (float*)d_out;

  // workspace: h_buf (TT*HH floats = 512 KB) | ready (TT*NB ints = 128 KB)
  float* h_buf = (float*)d_ws;
  int* ready = (int*)(h_buf + TT * HH);

  hipMemsetAsync(ready, 0, TT * NB * sizeof(int), stream);
  pg_rnn<<<dim3(NB), dim3(256), 0, stream>>>(x, h, Ws, bs, Wout, bout, h_buf,
                                             ready, out);
}